// Round 8
// baseline (146.383 us; speedup 1.0000x reference)
//
#include <hip/hip_runtime.h>

// RuleBasedEmbedding round 8: kill the serial prep tail (was ~30us alone on 1 CU:
// register-spilled token arrays + 16K contended LDS atomics).
//   zero     : 1 block, zero counts+done (no hipMemsetAsync -> graph-safe)
//   convhist : 800 convert blocks (M f32->bf16 B-fragment order, unchanged)
//              + 32 histogram blocks (1 token/thread, global atomicAdd)
//              + last-finishing block (atomic done-counter) runs plan
//   scatter  : 32 blocks, 1 token/thread, global atomic cursors
//   gemm     : unchanged (measured ~3-4us)
//
// out[t][e] = sum_d base[token_ids[t]][d] * M[rule[token_ids[t]]][d][e]
// 8192 tokens, D=256, 100 rules.

#define NTOK   8192
#define NRULE  100
#define DIM    256
#define TCH    32                        // tokens per chunk
#define MAXCH  384                       // >= 8192/32 + 100 = 356
#define GSTR   96                        // gemm blocks per XCD (x4 slots each)
#define LIST_SZ (NTOK + NRULE * TCH)     // 11392
#define NCONV  (NRULE * 8)               // 800 convert blocks
#define NHIST  32
#define NBLK_A (NCONV + NHIST)           // 832

// Bfrag: [r][ks=8][ct=16][lane=64][e=8] bf16 = 13,107,200 B
#define BFRAG_U16   (NRULE * 8 * 16 * 64 * 8)
#define WS_CTRL     (BFRAG_U16 / 2)              // int index base
#define WS_COUNTS   (WS_CTRL + 0)                // 100 counters
#define WS_DONE     (WS_CTRL + 120)
#define WS_CURSOR   (WS_CTRL + 128)              // 100 cursors
#define WS_CHRULE   (WS_CTRL + 256)
#define WS_LIST     (WS_CHRULE + MAXCH)
#define WS_PERM     (WS_LIST + LIST_SZ)
#define WS_TOTAL_INT (WS_PERM + 8 * MAXCH)
#define WS_BYTES    ((size_t)WS_TOTAL_INT * 4)   // ~13.2 MB

typedef __attribute__((ext_vector_type(8))) short bf16x8;   // 8 bf16 = 4 VGPR
typedef __attribute__((ext_vector_type(4))) float f32x4;    // MFMA C/D

__device__ __forceinline__ unsigned short f2bf(float f) {
    union { float f; unsigned int u; } c; c.f = f;
    unsigned int u = c.u;
    u = (u + 0x7FFFu + ((u >> 16) & 1u)) >> 16;   // RNE
    return (unsigned short)u;
}

// ---------------- zero control region ----------------
__global__ void zero_kernel(int* __restrict__ ws) {
    ws[WS_CTRL + threadIdx.x] = 0;                // counts + done (+ spare)
}

// ---------------- convert + histogram + last-block plan ----------------
__global__ __launch_bounds__(256)
void convhist_kernel(const int* __restrict__ token_ids,
                     const int* __restrict__ token_rules,
                     const float* __restrict__ M,
                     int* __restrict__ ws,
                     unsigned short* __restrict__ bf) {
    const int tid = threadIdx.x;
    const int bid = blockIdx.x;

    __shared__ unsigned short sb[32][DIM];        // convert slab (16 KB)
    __shared__ int s_cnt[NRULE], s_nch[NRULE], s_poff[NRULE];
    __shared__ int s_choff[NRULE + 1], s_xbase[NRULE];
    __shared__ int s_last;

    if (bid < NCONV) {
        // ---- convert slab M[r][ks*32..+31][:] -> Bfrag ----
        const int r  = bid >> 3;
        const int ks = bid & 7;
        const float4* M4 = reinterpret_cast<const float4*>(M) + ((size_t)r * 256 + ks * 32) * 64;
        #pragma unroll
        for (int j = 0; j < 8; ++j) {
            int idx = j * 256 + tid;              // 32 rows x 64 float4
            int kl = idx >> 6, c4 = idx & 63;
            float4 v = M4[kl * 64 + c4];
            sb[kl][c4 * 4 + 0] = f2bf(v.x);
            sb[kl][c4 * 4 + 1] = f2bf(v.y);
            sb[kl][c4 * 4 + 2] = f2bf(v.z);
            sb[kl][c4 * 4 + 3] = f2bf(v.w);
        }
        __syncthreads();

        // Bfrag[r][ks][ct][l][e] = M[r][ks*32 + (l>>4)*8 + e][ct*16 + (l&15)]
        uint4* outp = reinterpret_cast<uint4*>(bf) + ((size_t)(r * 8 + ks) * 16) * 64;
        #pragma unroll
        for (int it = 0; it < 4; ++it) {
            int w = it * 256 + tid;               // 16 ct x 64 lanes
            int ct = w >> 6, l = w & 63;
            int kb = (l >> 4) * 8, cc = ct * 16 + (l & 15);
            unsigned int d0 = sb[kb + 0][cc] | ((unsigned int)sb[kb + 1][cc] << 16);
            unsigned int d1 = sb[kb + 2][cc] | ((unsigned int)sb[kb + 3][cc] << 16);
            unsigned int d2 = sb[kb + 4][cc] | ((unsigned int)sb[kb + 5][cc] << 16);
            unsigned int d3 = sb[kb + 6][cc] | ((unsigned int)sb[kb + 7][cc] << 16);
            outp[ct * 64 + l] = make_uint4(d0, d1, d2, d3);
        }
    } else {
        // ---- histogram: 1 token per thread, global atomic (TCC-side) ----
        const int tok = (bid - NCONV) * 256 + tid;       // covers 0..8191
        const int id  = token_ids[tok];
        const int r   = token_rules[id];
        atomicAdd(&ws[WS_COUNTS + r], 1);
    }

    // ---- done-counter; last block runs plan ----
    __threadfence();                               // drain atomics/stores device-wide
    __syncthreads();
    if (tid == 0) {
        int v = atomicAdd(&ws[WS_DONE], 1);
        s_last = (v == NBLK_A - 1);
    }
    __syncthreads();
    if (!s_last) return;

    // ---- plan (one block, 256 threads) ----
    if (tid < NRULE) s_cnt[tid] = atomicAdd(&ws[WS_COUNTS + tid], 0);  // coherent read
    __syncthreads();
    if (tid == 0) {
        int po = 0, co = 0;
        int xc[8] = {0, 0, 0, 0, 0, 0, 0, 0};
        for (int r = 0; r < NRULE; ++r) {
            s_poff[r] = po; s_choff[r] = co;
            int n = (s_cnt[r] + TCH - 1) / TCH;
            s_nch[r] = n;
            s_xbase[r] = xc[r & 7];
            xc[r & 7] += n;
            po += n * TCH; co += n;
        }
        s_choff[NRULE] = co;
    }
    __syncthreads();

    if (tid < NRULE) ws[WS_CURSOR + tid] = s_poff[tid];
    for (int i = tid; i < 8 * MAXCH; i += 256) ws[WS_PERM + i] = -1;
    for (int i = tid; i < NRULE * TCH; i += 256) {       // pad slots
        int r = i >> 5, k = i & 31;
        int pos = s_poff[r] + s_cnt[r] + k;
        if (pos < s_poff[r] + s_nch[r] * TCH) ws[WS_LIST + pos] = -1;
    }
    __syncthreads();   // perm -1 fill complete before perm entry writes

    const int tc = s_choff[NRULE];
    for (int c = tid; c < tc; c += 256) {
        int lo = 0, hi = NRULE - 1;            // largest r with choff[r] <= c
        while (lo < hi) {
            int mid = (lo + hi + 1) >> 1;
            if (s_choff[mid] <= c) lo = mid; else hi = mid - 1;
        }
        ws[WS_CHRULE + c] = lo;
        ws[WS_PERM + (lo & 7) * MAXCH + s_xbase[lo] + (c - s_choff[lo])] = c;
    }
}

// ---------------- scatter: 1 token per thread, global atomic cursors ----------------
// Chunk composition is race-ordered, but each token's output row is bitwise
// independent of its slot (own A-row x own rule matrix, fixed MFMA k-order).
__global__ __launch_bounds__(256)
void scatter_kernel(const int* __restrict__ token_ids,
                    const int* __restrict__ token_rules, int* __restrict__ ws) {
    const int tok = blockIdx.x * 256 + threadIdx.x;      // 32 blocks -> 8192
    const int id  = token_ids[tok];
    const int r   = token_rules[id];
    const int pos = atomicAdd(&ws[WS_CURSOR + r], 1);
    ws[WS_LIST + pos] = tok;
}

// ---------------- gemm: chunk (32 tokens) x rule matrix via MFMA ----------------
__global__ __launch_bounds__(256)
void gemm_kernel(const int* __restrict__ token_ids,
                 const float* __restrict__ base_emb,
                 const int* __restrict__ ws,
                 const unsigned short* __restrict__ bfrag,
                 float* __restrict__ out) {
    const int xcd  = blockIdx.x & 7;
    const int base = blockIdx.x >> 3;               // 0..GSTR-1
    const int tid  = threadIdx.x;
    const int wave = tid >> 6, lane = tid & 63;

    __shared__ unsigned short sa[8 * 2 * 64 * 8];   // 16 KB: [ks][tt][lane][e]
    __shared__ int sst[TCH];

    for (int slot = base; slot < MAXCH; slot += GSTR) {
        const int c = ws[WS_PERM + xcd * MAXCH + slot];
        if (c < 0) return;                          // compacted: uniform exit
        const int r = ws[WS_CHRULE + c];

        __syncthreads();                            // sa/sst safe to overwrite
        if (tid < TCH) sst[tid] = ws[WS_LIST + c * TCH + tid];
        __syncthreads();

        {   // stage A: thread = (token slot s, kstep ksl)
            const int s = tid >> 3, ksl = tid & 7;
            const int pos = sst[s];
            const int tt = s >> 4, lr = s & 15;
            const float4* row4 = nullptr;
            if (pos >= 0)
                row4 = reinterpret_cast<const float4*>(base_emb + (size_t)token_ids[pos] * DIM);
            #pragma unroll
            for (int j = 0; j < 8; ++j) {
                float4 v = row4 ? row4[ksl * 8 + j] : make_float4(0.f, 0.f, 0.f, 0.f);
                const int l = lr | ((j >> 1) << 4);
                const int e0 = (j & 1) * 4;
                ushort4 p;
                p.x = f2bf(v.x); p.y = f2bf(v.y); p.z = f2bf(v.z); p.w = f2bf(v.w);
                *reinterpret_cast<ushort4*>(&sa[((ksl * 2 + tt) * 64 + l) * 8 + e0]) = p;
            }
        }
        __syncthreads();

        f32x4 acc[2][4];
        #pragma unroll
        for (int tt = 0; tt < 2; ++tt)
            #pragma unroll
            for (int ctl = 0; ctl < 4; ++ctl)
                acc[tt][ctl] = (f32x4){0.f, 0.f, 0.f, 0.f};

        const bf16x8* Af = reinterpret_cast<const bf16x8*>(sa);
        const bf16x8* Bf = reinterpret_cast<const bf16x8*>(bfrag) + (size_t)r * 8 * 16 * 64;

        #pragma unroll
        for (int ks = 0; ks < 8; ++ks) {
            const bf16x8 a0 = Af[(ks * 2 + 0) * 64 + lane];
            const bf16x8 a1 = Af[(ks * 2 + 1) * 64 + lane];
            const bf16x8 b0 = Bf[(ks * 16 + wave * 4 + 0) * 64 + lane];
            const bf16x8 b1 = Bf[(ks * 16 + wave * 4 + 1) * 64 + lane];
            const bf16x8 b2 = Bf[(ks * 16 + wave * 4 + 2) * 64 + lane];
            const bf16x8 b3 = Bf[(ks * 16 + wave * 4 + 3) * 64 + lane];
            acc[0][0] = __builtin_amdgcn_mfma_f32_16x16x32_bf16(a0, b0, acc[0][0], 0, 0, 0);
            acc[0][1] = __builtin_amdgcn_mfma_f32_16x16x32_bf16(a0, b1, acc[0][1], 0, 0, 0);
            acc[0][2] = __builtin_amdgcn_mfma_f32_16x16x32_bf16(a0, b2, acc[0][2], 0, 0, 0);
            acc[0][3] = __builtin_amdgcn_mfma_f32_16x16x32_bf16(a0, b3, acc[0][3], 0, 0, 0);
            acc[1][0] = __builtin_amdgcn_mfma_f32_16x16x32_bf16(a1, b0, acc[1][0], 0, 0, 0);
            acc[1][1] = __builtin_amdgcn_mfma_f32_16x16x32_bf16(a1, b1, acc[1][1], 0, 0, 0);
            acc[1][2] = __builtin_amdgcn_mfma_f32_16x16x32_bf16(a1, b2, acc[1][2], 0, 0, 0);
            acc[1][3] = __builtin_amdgcn_mfma_f32_16x16x32_bf16(a1, b3, acc[1][3], 0, 0, 0);
        }

        // D layout: col = lane&15, row = (lane>>4)*4 + reg
        #pragma unroll
        for (int tt = 0; tt < 2; ++tt) {
            #pragma unroll
            for (int reg = 0; reg < 4; ++reg) {
                const int row = tt * 16 + (lane >> 4) * 4 + reg;
                const int pos = sst[row];
                if (pos >= 0) {
                    #pragma unroll
                    for (int ctl = 0; ctl < 4; ++ctl) {
                        const int col = (wave * 4 + ctl) * 16 + (lane & 15);
                        out[(size_t)pos * DIM + col] = acc[tt][ctl][reg];
                    }
                }
            }
        }
    }
}

// ---------------- fallback (round-1 kernel) if ws too small ----------------
__global__ __launch_bounds__(256, 4)
void rule_embed_fallback(const int* __restrict__ token_ids,
                         const float* __restrict__ base_emb,
                         const float* __restrict__ rule_mats,
                         const int* __restrict__ token_rules,
                         float* __restrict__ out, int n_tokens) {
    const int wave = threadIdx.x >> 6, lane = threadIdx.x & 63;
    const int tok = blockIdx.x * 4 + wave;
    __shared__ float base[4][DIM];
    if (tok < n_tokens) {
        const int tid = token_ids[tok];
        reinterpret_cast<float4*>(base[wave])[lane] =
            reinterpret_cast<const float4*>(base_emb + (size_t)tid * DIM)[lane];
    }
    __syncthreads();
    if (tok >= n_tokens) return;
    const int tid = token_ids[tok];
    const int r = token_rules[tid];
    const float4* M4 = reinterpret_cast<const float4*>(rule_mats + (size_t)r * DIM * DIM);
    float4 acc = make_float4(0.f, 0.f, 0.f, 0.f);
    #pragma unroll 8
    for (int d = 0; d < DIM; ++d) {
        const float b = base[wave][d];
        const float4 m = M4[d * (DIM / 4) + lane];
        acc.x += b * m.x; acc.y += b * m.y; acc.z += b * m.z; acc.w += b * m.w;
    }
    reinterpret_cast<float4*>(out + (size_t)tok * DIM)[lane] = acc;
}

extern "C" void kernel_launch(void* const* d_in, const int* in_sizes, int n_in,
                              void* d_out, int out_size, void* d_ws, size_t ws_size,
                              hipStream_t stream) {
    const int*   token_ids   = (const int*)d_in[0];    // [4, 2048]
    const float* base_emb    = (const float*)d_in[1];  // [32000, 256]
    const float* rule_mats   = (const float*)d_in[2];  // [100, 256, 256]
    const int*   token_rules = (const int*)d_in[3];    // [32000]
    float*       out         = (float*)d_out;          // [4, 2048, 256]

    if (ws_size < WS_BYTES) {
        rule_embed_fallback<<<(NTOK + 3) / 4, 256, 0, stream>>>(
            token_ids, base_emb, rule_mats, token_rules, out, NTOK);
        return;
    }

    int*            ws = (int*)d_ws;
    unsigned short* bf = (unsigned short*)d_ws;

    zero_kernel<<<1, 128, 0, stream>>>(ws);
    convhist_kernel<<<NBLK_A, 256, 0, stream>>>(token_ids, token_rules, rule_mats, ws, bf);
    scatter_kernel<<<NHIST, 256, 0, stream>>>(token_ids, token_rules, ws);
    gemm_kernel<<<8 * GSTR, 256, 0, stream>>>(token_ids, base_emb, ws, bf, out);
}

// Round 9
// 58.924 us; speedup vs baseline: 2.4843x; 2.4843x over previous
//
#include <hip/hip_runtime.h>

// RuleBasedEmbedding round 9: revert the in-kernel device fence (832 per-block
// L2 writeback/invalidates = 120us!). Stream-ordered small kernels instead —
// kernel boundaries provide device-wide visibility ONCE each.
//   zero     : zero rule counters (graph-safe)
//   convhist : 800 convert blocks (M f32->bf16, B-fragment order)
//              + 32 histogram blocks (1 token/thread, global atomicAdd). No fence.
//   plan     : 1 block: prefix scan, cursors, pad slots, per-XCD perm
//   scatter  : 32 blocks, global atomic cursors
//   gemm     : chunk (32 same-rule tokens) x rule matrix via MFMA (unchanged)
//
// out[t][e] = sum_d base[token_ids[t]][d] * M[rule[token_ids[t]]][d][e]
// 8192 tokens, D=256, 100 rules.

#define NTOK   8192
#define NRULE  100
#define DIM    256
#define TCH    32                        // tokens per chunk
#define MAXCH  384                       // >= 8192/32 + 100 = 356
#define GSTR   96                        // gemm blocks per XCD (x4 slots each)
#define LIST_SZ (NTOK + NRULE * TCH)     // 11392
#define NCONV  (NRULE * 8)               // 800 convert blocks
#define NHIST  32
#define NBLK_A (NCONV + NHIST)           // 832

// Bfrag: [r][ks=8][ct=16][lane=64][e=8] bf16 = 13,107,200 B
#define BFRAG_U16   (NRULE * 8 * 16 * 64 * 8)
#define WS_CTRL     (BFRAG_U16 / 2)              // int index base
#define WS_COUNTS   (WS_CTRL + 0)                // 100 counters
#define WS_CURSOR   (WS_CTRL + 128)              // 100 cursors
#define WS_CHRULE   (WS_CTRL + 256)
#define WS_LIST     (WS_CHRULE + MAXCH)
#define WS_PERM     (WS_LIST + LIST_SZ)
#define WS_TOTAL_INT (WS_PERM + 8 * MAXCH)
#define WS_BYTES    ((size_t)WS_TOTAL_INT * 4)   // ~13.2 MB

typedef __attribute__((ext_vector_type(8))) short bf16x8;   // 8 bf16 = 4 VGPR
typedef __attribute__((ext_vector_type(4))) float f32x4;    // MFMA C/D

__device__ __forceinline__ unsigned short f2bf(float f) {
    union { float f; unsigned int u; } c; c.f = f;
    unsigned int u = c.u;
    u = (u + 0x7FFFu + ((u >> 16) & 1u)) >> 16;   // RNE
    return (unsigned short)u;
}

// ---------------- zero counters ----------------
__global__ void zero_kernel(int* __restrict__ ws) {
    ws[WS_CTRL + threadIdx.x] = 0;                // counts (+ spare)
}

// ---------------- convert + histogram (no fence, no plan) ----------------
__global__ __launch_bounds__(256)
void convhist_kernel(const int* __restrict__ token_ids,
                     const int* __restrict__ token_rules,
                     const float* __restrict__ M,
                     int* __restrict__ ws,
                     unsigned short* __restrict__ bf) {
    const int tid = threadIdx.x;
    const int bid = blockIdx.x;

    if (bid >= NCONV) {
        // ---- histogram: 1 token per thread, global atomic (TCC-side) ----
        const int tok = (bid - NCONV) * 256 + tid;       // covers 0..8191
        const int id  = token_ids[tok];
        const int r   = token_rules[id];
        atomicAdd(&ws[WS_COUNTS + r], 1);
        return;
    }

    // ---- convert slab M[r][ks*32..+31][:] -> Bfrag ----
    __shared__ unsigned short sb[32][DIM];        // 16 KB row-major bf16 slab
    const int r  = bid >> 3;
    const int ks = bid & 7;
    const float4* M4 = reinterpret_cast<const float4*>(M) + ((size_t)r * 256 + ks * 32) * 64;
    #pragma unroll
    for (int j = 0; j < 8; ++j) {
        int idx = j * 256 + tid;              // 32 rows x 64 float4
        int kl = idx >> 6, c4 = idx & 63;
        float4 v = M4[kl * 64 + c4];
        sb[kl][c4 * 4 + 0] = f2bf(v.x);
        sb[kl][c4 * 4 + 1] = f2bf(v.y);
        sb[kl][c4 * 4 + 2] = f2bf(v.z);
        sb[kl][c4 * 4 + 3] = f2bf(v.w);
    }
    __syncthreads();

    // Bfrag[r][ks][ct][l][e] = M[r][ks*32 + (l>>4)*8 + e][ct*16 + (l&15)]
    uint4* outp = reinterpret_cast<uint4*>(bf) + ((size_t)(r * 8 + ks) * 16) * 64;
    #pragma unroll
    for (int it = 0; it < 4; ++it) {
        int w = it * 256 + tid;               // 16 ct x 64 lanes
        int ct = w >> 6, l = w & 63;
        int kb = (l >> 4) * 8, cc = ct * 16 + (l & 15);
        unsigned int d0 = sb[kb + 0][cc] | ((unsigned int)sb[kb + 1][cc] << 16);
        unsigned int d1 = sb[kb + 2][cc] | ((unsigned int)sb[kb + 3][cc] << 16);
        unsigned int d2 = sb[kb + 4][cc] | ((unsigned int)sb[kb + 5][cc] << 16);
        unsigned int d3 = sb[kb + 6][cc] | ((unsigned int)sb[kb + 7][cc] << 16);
        outp[ct * 64 + l] = make_uint4(d0, d1, d2, d3);
    }
}

// ---------------- plan: 1 block ----------------
__global__ __launch_bounds__(256)
void plan_kernel(int* __restrict__ ws) {
    __shared__ int s_cnt[NRULE], s_nch[NRULE], s_poff[NRULE];
    __shared__ int s_choff[NRULE + 1], s_xbase[NRULE];
    const int tid = threadIdx.x;

    if (tid < NRULE) s_cnt[tid] = ws[WS_COUNTS + tid];
    __syncthreads();
    if (tid == 0) {
        int po = 0, co = 0;
        int xc[8] = {0, 0, 0, 0, 0, 0, 0, 0};
        for (int r = 0; r < NRULE; ++r) {
            s_poff[r] = po; s_choff[r] = co;
            int n = (s_cnt[r] + TCH - 1) / TCH;
            s_nch[r] = n;
            s_xbase[r] = xc[r & 7];
            xc[r & 7] += n;
            po += n * TCH; co += n;
        }
        s_choff[NRULE] = co;
    }
    __syncthreads();

    if (tid < NRULE) ws[WS_CURSOR + tid] = s_poff[tid];
    for (int i = tid; i < 8 * MAXCH; i += 256) ws[WS_PERM + i] = -1;
    for (int i = tid; i < NRULE * TCH; i += 256) {       // pad slots
        int r = i >> 5, k = i & 31;
        int pos = s_poff[r] + s_cnt[r] + k;
        if (pos < s_poff[r] + s_nch[r] * TCH) ws[WS_LIST + pos] = -1;
    }
    __syncthreads();   // perm -1 fill complete before perm entry writes

    const int tc = s_choff[NRULE];
    for (int c = tid; c < tc; c += 256) {
        int lo = 0, hi = NRULE - 1;            // largest r with choff[r] <= c
        while (lo < hi) {
            int mid = (lo + hi + 1) >> 1;
            if (s_choff[mid] <= c) lo = mid; else hi = mid - 1;
        }
        ws[WS_CHRULE + c] = lo;
        ws[WS_PERM + (lo & 7) * MAXCH + s_xbase[lo] + (c - s_choff[lo])] = c;
    }
}

// ---------------- scatter: 1 token per thread, global atomic cursors ----------------
// Chunk composition is race-ordered, but each token's output row is bitwise
// independent of its slot (own A-row x own rule matrix, fixed MFMA k-order).
__global__ __launch_bounds__(256)
void scatter_kernel(const int* __restrict__ token_ids,
                    const int* __restrict__ token_rules, int* __restrict__ ws) {
    const int tok = blockIdx.x * 256 + threadIdx.x;      // 32 blocks -> 8192
    const int id  = token_ids[tok];
    const int r   = token_rules[id];
    const int pos = atomicAdd(&ws[WS_CURSOR + r], 1);
    ws[WS_LIST + pos] = tok;
}

// ---------------- gemm: chunk (32 tokens) x rule matrix via MFMA ----------------
__global__ __launch_bounds__(256)
void gemm_kernel(const int* __restrict__ token_ids,
                 const float* __restrict__ base_emb,
                 const int* __restrict__ ws,
                 const unsigned short* __restrict__ bfrag,
                 float* __restrict__ out) {
    const int xcd  = blockIdx.x & 7;
    const int base = blockIdx.x >> 3;               // 0..GSTR-1
    const int tid  = threadIdx.x;
    const int wave = tid >> 6, lane = tid & 63;

    __shared__ unsigned short sa[8 * 2 * 64 * 8];   // 16 KB: [ks][tt][lane][e]
    __shared__ int sst[TCH];

    for (int slot = base; slot < MAXCH; slot += GSTR) {
        const int c = ws[WS_PERM + xcd * MAXCH + slot];
        if (c < 0) return;                          // compacted: uniform exit
        const int r = ws[WS_CHRULE + c];

        __syncthreads();                            // sa/sst safe to overwrite
        if (tid < TCH) sst[tid] = ws[WS_LIST + c * TCH + tid];
        __syncthreads();

        {   // stage A: thread = (token slot s, kstep ksl)
            const int s = tid >> 3, ksl = tid & 7;
            const int pos = sst[s];
            const int tt = s >> 4, lr = s & 15;
            const float4* row4 = nullptr;
            if (pos >= 0)
                row4 = reinterpret_cast<const float4*>(base_emb + (size_t)token_ids[pos] * DIM);
            #pragma unroll
            for (int j = 0; j < 8; ++j) {
                float4 v = row4 ? row4[ksl * 8 + j] : make_float4(0.f, 0.f, 0.f, 0.f);
                const int l = lr | ((j >> 1) << 4);
                const int e0 = (j & 1) * 4;
                ushort4 p;
                p.x = f2bf(v.x); p.y = f2bf(v.y); p.z = f2bf(v.z); p.w = f2bf(v.w);
                *reinterpret_cast<ushort4*>(&sa[((ksl * 2 + tt) * 64 + l) * 8 + e0]) = p;
            }
        }
        __syncthreads();

        f32x4 acc[2][4];
        #pragma unroll
        for (int tt = 0; tt < 2; ++tt)
            #pragma unroll
            for (int ctl = 0; ctl < 4; ++ctl)
                acc[tt][ctl] = (f32x4){0.f, 0.f, 0.f, 0.f};

        const bf16x8* Af = reinterpret_cast<const bf16x8*>(sa);
        const bf16x8* Bf = reinterpret_cast<const bf16x8*>(bfrag) + (size_t)r * 8 * 16 * 64;

        #pragma unroll
        for (int ks = 0; ks < 8; ++ks) {
            const bf16x8 a0 = Af[(ks * 2 + 0) * 64 + lane];
            const bf16x8 a1 = Af[(ks * 2 + 1) * 64 + lane];
            const bf16x8 b0 = Bf[(ks * 16 + wave * 4 + 0) * 64 + lane];
            const bf16x8 b1 = Bf[(ks * 16 + wave * 4 + 1) * 64 + lane];
            const bf16x8 b2 = Bf[(ks * 16 + wave * 4 + 2) * 64 + lane];
            const bf16x8 b3 = Bf[(ks * 16 + wave * 4 + 3) * 64 + lane];
            acc[0][0] = __builtin_amdgcn_mfma_f32_16x16x32_bf16(a0, b0, acc[0][0], 0, 0, 0);
            acc[0][1] = __builtin_amdgcn_mfma_f32_16x16x32_bf16(a0, b1, acc[0][1], 0, 0, 0);
            acc[0][2] = __builtin_amdgcn_mfma_f32_16x16x32_bf16(a0, b2, acc[0][2], 0, 0, 0);
            acc[0][3] = __builtin_amdgcn_mfma_f32_16x16x32_bf16(a0, b3, acc[0][3], 0, 0, 0);
            acc[1][0] = __builtin_amdgcn_mfma_f32_16x16x32_bf16(a1, b0, acc[1][0], 0, 0, 0);
            acc[1][1] = __builtin_amdgcn_mfma_f32_16x16x32_bf16(a1, b1, acc[1][1], 0, 0, 0);
            acc[1][2] = __builtin_amdgcn_mfma_f32_16x16x32_bf16(a1, b2, acc[1][2], 0, 0, 0);
            acc[1][3] = __builtin_amdgcn_mfma_f32_16x16x32_bf16(a1, b3, acc[1][3], 0, 0, 0);
        }

        // D layout: col = lane&15, row = (lane>>4)*4 + reg
        #pragma unroll
        for (int tt = 0; tt < 2; ++tt) {
            #pragma unroll
            for (int reg = 0; reg < 4; ++reg) {
                const int row = tt * 16 + (lane >> 4) * 4 + reg;
                const int pos = sst[row];
                if (pos >= 0) {
                    #pragma unroll
                    for (int ctl = 0; ctl < 4; ++ctl) {
                        const int col = (wave * 4 + ctl) * 16 + (lane & 15);
                        out[(size_t)pos * DIM + col] = acc[tt][ctl][reg];
                    }
                }
            }
        }
    }
}

// ---------------- fallback (round-1 kernel) if ws too small ----------------
__global__ __launch_bounds__(256, 4)
void rule_embed_fallback(const int* __restrict__ token_ids,
                         const float* __restrict__ base_emb,
                         const float* __restrict__ rule_mats,
                         const int* __restrict__ token_rules,
                         float* __restrict__ out, int n_tokens) {
    const int wave = threadIdx.x >> 6, lane = threadIdx.x & 63;
    const int tok = blockIdx.x * 4 + wave;
    __shared__ float base[4][DIM];
    if (tok < n_tokens) {
        const int tid = token_ids[tok];
        reinterpret_cast<float4*>(base[wave])[lane] =
            reinterpret_cast<const float4*>(base_emb + (size_t)tid * DIM)[lane];
    }
    __syncthreads();
    if (tok >= n_tokens) return;
    const int tid = token_ids[tok];
    const int r = token_rules[tid];
    const float4* M4 = reinterpret_cast<const float4*>(rule_mats + (size_t)r * DIM * DIM);
    float4 acc = make_float4(0.f, 0.f, 0.f, 0.f);
    #pragma unroll 8
    for (int d = 0; d < DIM; ++d) {
        const float b = base[wave][d];
        const float4 m = M4[d * (DIM / 4) + lane];
        acc.x += b * m.x; acc.y += b * m.y; acc.z += b * m.z; acc.w += b * m.w;
    }
    reinterpret_cast<float4*>(out + (size_t)tok * DIM)[lane] = acc;
}

extern "C" void kernel_launch(void* const* d_in, const int* in_sizes, int n_in,
                              void* d_out, int out_size, void* d_ws, size_t ws_size,
                              hipStream_t stream) {
    const int*   token_ids   = (const int*)d_in[0];    // [4, 2048]
    const float* base_emb    = (const float*)d_in[1];  // [32000, 256]
    const float* rule_mats   = (const float*)d_in[2];  // [100, 256, 256]
    const int*   token_rules = (const int*)d_in[3];    // [32000]
    float*       out         = (float*)d_out;          // [4, 2048, 256]

    if (ws_size < WS_BYTES) {
        rule_embed_fallback<<<(NTOK + 3) / 4, 256, 0, stream>>>(
            token_ids, base_emb, rule_mats, token_rules, out, NTOK);
        return;
    }

    int*            ws = (int*)d_ws;
    unsigned short* bf = (unsigned short*)d_ws;

    zero_kernel<<<1, 128, 0, stream>>>(ws);
    convhist_kernel<<<NBLK_A, 256, 0, stream>>>(token_ids, token_rules, rule_mats, ws, bf);
    plan_kernel<<<1, 256, 0, stream>>>(ws);
    scatter_kernel<<<NHIST, 256, 0, stream>>>(token_ids, token_rules, ws);
    gemm_kernel<<<8 * GSTR, 256, 0, stream>>>(token_ids, base_emb, ws, bf, out);
}

// Round 10
// 34.104 us; speedup vs baseline: 4.2922x; 1.7278x over previous
//
#include <hip/hip_runtime.h>

// RuleBasedEmbedding round 10: 3-node pipeline (node fixed-cost was the killer:
// 5-node runs carry ~5-10us per extra node; R7's 2-node gap was 0.6us).
//   zero        : zero 100 rule cursors (1 block)
//   conv_scatter: 800 convert blocks (M f32->bf16, B-fragment order)
//                 + 32 scatter blocks: pos=atomicAdd(cursor[r]) -> list[r*8192+pos].
//                 No histogram, no plan, no perm: fixed-capacity per-rule regions
//                 (ws is 256MB — fillBuffer evidence).  Disjoint ws regions -> no
//                 intra-kernel ordering needed.
//   gemm        : block class=bid&7 reads its 13 rules' counts (=cursors),
//                 builds chunk prefix in LDS, strides chunks; pad = idx>=cnt.
//
// out[t][e] = sum_d base[token_ids[t]][d] * M[rule[token_ids[t]]][d][e]
// 8192 tokens, D=256, 100 rules.

#define NTOK   8192
#define NRULE  100
#define DIM    256
#define TCH    32                        // tokens per chunk
#define RCAP   NTOK                      // per-rule list capacity (safe any skew)
#define GSTR   64                        // gemm blocks per XCD class
#define NCONV  (NRULE * 8)               // 800 convert blocks
#define NSCAT  32
#define NBLK_A (NCONV + NSCAT)           // 832

// Bfrag: [r][ks=8][ct=16][lane=64][e=8] bf16 = 13,107,200 B
#define BFRAG_U16   (NRULE * 8 * 16 * 64 * 8)
#define WS_CUR      (BFRAG_U16 / 2)              // 100 cursors (pad to 128)
#define WS_LIST     (WS_CUR + 128)               // 100 x 8192 token slots
#define WS_TOTAL_INT (WS_LIST + NRULE * RCAP)
#define WS_BYTES    ((size_t)WS_TOTAL_INT * 4)   // ~16.4 MB

typedef __attribute__((ext_vector_type(8))) short bf16x8;   // 8 bf16 = 4 VGPR
typedef __attribute__((ext_vector_type(4))) float f32x4;    // MFMA C/D

__device__ __forceinline__ unsigned short f2bf(float f) {
    union { float f; unsigned int u; } c; c.f = f;
    unsigned int u = c.u;
    u = (u + 0x7FFFu + ((u >> 16) & 1u)) >> 16;   // RNE
    return (unsigned short)u;
}

// ---------------- zero cursors ----------------
__global__ void zero_kernel(int* __restrict__ ws) {
    ws[WS_CUR + threadIdx.x] = 0;                 // 128 threads cover cursors
}

// ---------------- convert + scatter (disjoint regions, no fence) ----------------
__global__ __launch_bounds__(256)
void conv_scatter_kernel(const int* __restrict__ token_ids,
                         const int* __restrict__ token_rules,
                         const float* __restrict__ M,
                         int* __restrict__ ws,
                         unsigned short* __restrict__ bf) {
    const int tid = threadIdx.x;
    const int bid = blockIdx.x;

    if (bid >= NCONV) {
        // ---- scatter: 1 token/thread, global atomic cursor = slot AND count ----
        const int tok = (bid - NCONV) * 256 + tid;       // covers 0..8191
        const int id  = token_ids[tok];
        const int r   = token_rules[id];
        const int pos = atomicAdd(&ws[WS_CUR + r], 1);
        ws[WS_LIST + r * RCAP + pos] = tok;
        return;
    }

    // ---- convert slab M[r][ks*32..+31][:] -> Bfrag ----
    __shared__ unsigned short sb[32][DIM];        // 16 KB row-major bf16 slab
    const int r  = bid >> 3;
    const int ks = bid & 7;
    const float4* M4 = reinterpret_cast<const float4*>(M) + ((size_t)r * 256 + ks * 32) * 64;
    #pragma unroll
    for (int j = 0; j < 8; ++j) {
        int idx = j * 256 + tid;                  // 32 rows x 64 float4
        int kl = idx >> 6, c4 = idx & 63;
        float4 v = M4[kl * 64 + c4];
        sb[kl][c4 * 4 + 0] = f2bf(v.x);
        sb[kl][c4 * 4 + 1] = f2bf(v.y);
        sb[kl][c4 * 4 + 2] = f2bf(v.z);
        sb[kl][c4 * 4 + 3] = f2bf(v.w);
    }
    __syncthreads();

    // Bfrag[r][ks][ct][l][e] = M[r][ks*32 + (l>>4)*8 + e][ct*16 + (l&15)]
    uint4* outp = reinterpret_cast<uint4*>(bf) + ((size_t)(r * 8 + ks) * 16) * 64;
    #pragma unroll
    for (int it = 0; it < 4; ++it) {
        int w = it * 256 + tid;                   // 16 ct x 64 lanes
        int ct = w >> 6, l = w & 63;
        int kb = (l >> 4) * 8, cc = ct * 16 + (l & 15);
        unsigned int d0 = sb[kb + 0][cc] | ((unsigned int)sb[kb + 1][cc] << 16);
        unsigned int d1 = sb[kb + 2][cc] | ((unsigned int)sb[kb + 3][cc] << 16);
        unsigned int d2 = sb[kb + 4][cc] | ((unsigned int)sb[kb + 5][cc] << 16);
        unsigned int d3 = sb[kb + 6][cc] | ((unsigned int)sb[kb + 7][cc] << 16);
        outp[ct * 64 + l] = make_uint4(d0, d1, d2, d3);
    }
}

// ---------------- gemm: self-enumerating chunks via per-class prefix ----------------
__global__ __launch_bounds__(256)
void gemm_kernel(const int* __restrict__ token_ids,
                 const float* __restrict__ base_emb,
                 const int* __restrict__ ws,
                 const unsigned short* __restrict__ bfrag,
                 float* __restrict__ out) {
    const int xcd  = blockIdx.x & 7;
    const int base = blockIdx.x >> 3;               // 0..GSTR-1
    const int tid  = threadIdx.x;
    const int wave = tid >> 6, lane = tid & 63;

    __shared__ unsigned short sa[8 * 2 * 64 * 8];   // 16 KB: [ks][tt][lane][e]
    __shared__ int sst[TCH];
    __shared__ int s_rcnt[13], s_choff[14];

    if (tid < 13) {
        int r = xcd + 8 * tid;                      // class rules: xcd, xcd+8, ...
        s_rcnt[tid] = (r < NRULE) ? ws[WS_CUR + r] : 0;
    }
    __syncthreads();
    if (tid == 0) {
        int acc = 0; s_choff[0] = 0;
        #pragma unroll
        for (int i = 0; i < 13; ++i) { acc += (s_rcnt[i] + TCH - 1) / TCH; s_choff[i + 1] = acc; }
    }
    __syncthreads();
    const int total = s_choff[13];

    for (int slot = base; slot < total; slot += GSTR) {
        int i = 0;                                  // largest k with choff[k] <= slot
        #pragma unroll
        for (int k = 1; k < 13; ++k) if (slot >= s_choff[k]) i = k;
        const int r   = xcd + 8 * i;
        const int j   = slot - s_choff[i];
        const int cnt = s_rcnt[i];

        __syncthreads();                            // sa/sst safe to overwrite
        if (tid < TCH) {
            int idx = j * TCH + tid;
            sst[tid] = (idx < cnt) ? ws[WS_LIST + r * RCAP + idx] : -1;
        }
        __syncthreads();

        {   // stage A: thread = (token slot s, kstep ksl)
            const int s = tid >> 3, ksl = tid & 7;
            const int pos = sst[s];
            const int tt = s >> 4, lr = s & 15;
            const float4* row4 = nullptr;
            if (pos >= 0)
                row4 = reinterpret_cast<const float4*>(base_emb + (size_t)token_ids[pos] * DIM);
            #pragma unroll
            for (int jj = 0; jj < 8; ++jj) {
                float4 v = row4 ? row4[ksl * 8 + jj] : make_float4(0.f, 0.f, 0.f, 0.f);
                const int l = lr | ((jj >> 1) << 4);
                const int e0 = (jj & 1) * 4;
                ushort4 p;
                p.x = f2bf(v.x); p.y = f2bf(v.y); p.z = f2bf(v.z); p.w = f2bf(v.w);
                *reinterpret_cast<ushort4*>(&sa[((ksl * 2 + tt) * 64 + l) * 8 + e0]) = p;
            }
        }
        __syncthreads();

        f32x4 acc[2][4];
        #pragma unroll
        for (int tt = 0; tt < 2; ++tt)
            #pragma unroll
            for (int ctl = 0; ctl < 4; ++ctl)
                acc[tt][ctl] = (f32x4){0.f, 0.f, 0.f, 0.f};

        const bf16x8* Af = reinterpret_cast<const bf16x8*>(sa);
        const bf16x8* Bf = reinterpret_cast<const bf16x8*>(bfrag) + (size_t)r * 8 * 16 * 64;

        #pragma unroll
        for (int ks = 0; ks < 8; ++ks) {
            const bf16x8 a0 = Af[(ks * 2 + 0) * 64 + lane];
            const bf16x8 a1 = Af[(ks * 2 + 1) * 64 + lane];
            const bf16x8 b0 = Bf[(ks * 16 + wave * 4 + 0) * 64 + lane];
            const bf16x8 b1 = Bf[(ks * 16 + wave * 4 + 1) * 64 + lane];
            const bf16x8 b2 = Bf[(ks * 16 + wave * 4 + 2) * 64 + lane];
            const bf16x8 b3 = Bf[(ks * 16 + wave * 4 + 3) * 64 + lane];
            acc[0][0] = __builtin_amdgcn_mfma_f32_16x16x32_bf16(a0, b0, acc[0][0], 0, 0, 0);
            acc[0][1] = __builtin_amdgcn_mfma_f32_16x16x32_bf16(a0, b1, acc[0][1], 0, 0, 0);
            acc[0][2] = __builtin_amdgcn_mfma_f32_16x16x32_bf16(a0, b2, acc[0][2], 0, 0, 0);
            acc[0][3] = __builtin_amdgcn_mfma_f32_16x16x32_bf16(a0, b3, acc[0][3], 0, 0, 0);
            acc[1][0] = __builtin_amdgcn_mfma_f32_16x16x32_bf16(a1, b0, acc[1][0], 0, 0, 0);
            acc[1][1] = __builtin_amdgcn_mfma_f32_16x16x32_bf16(a1, b1, acc[1][1], 0, 0, 0);
            acc[1][2] = __builtin_amdgcn_mfma_f32_16x16x32_bf16(a1, b2, acc[1][2], 0, 0, 0);
            acc[1][3] = __builtin_amdgcn_mfma_f32_16x16x32_bf16(a1, b3, acc[1][3], 0, 0, 0);
        }

        // D layout: col = lane&15, row = (lane>>4)*4 + reg
        #pragma unroll
        for (int tt = 0; tt < 2; ++tt) {
            #pragma unroll
            for (int reg = 0; reg < 4; ++reg) {
                const int row = tt * 16 + (lane >> 4) * 4 + reg;
                const int pos = sst[row];
                if (pos >= 0) {
                    #pragma unroll
                    for (int ctl = 0; ctl < 4; ++ctl) {
                        const int col = (wave * 4 + ctl) * 16 + (lane & 15);
                        out[(size_t)pos * DIM + col] = acc[tt][ctl][reg];
                    }
                }
            }
        }
    }
}

// ---------------- fallback (round-1 kernel) if ws too small ----------------
__global__ __launch_bounds__(256, 4)
void rule_embed_fallback(const int* __restrict__ token_ids,
                         const float* __restrict__ base_emb,
                         const float* __restrict__ rule_mats,
                         const int* __restrict__ token_rules,
                         float* __restrict__ out, int n_tokens) {
    const int wave = threadIdx.x >> 6, lane = threadIdx.x & 63;
    const int tok = blockIdx.x * 4 + wave;
    __shared__ float base[4][DIM];
    if (tok < n_tokens) {
        const int tid = token_ids[tok];
        reinterpret_cast<float4*>(base[wave])[lane] =
            reinterpret_cast<const float4*>(base_emb + (size_t)tid * DIM)[lane];
    }
    __syncthreads();
    if (tok >= n_tokens) return;
    const int tid = token_ids[tok];
    const int r = token_rules[tid];
    const float4* M4 = reinterpret_cast<const float4*>(rule_mats + (size_t)r * DIM * DIM);
    float4 acc = make_float4(0.f, 0.f, 0.f, 0.f);
    #pragma unroll 8
    for (int d = 0; d < DIM; ++d) {
        const float b = base[wave][d];
        const float4 m = M4[d * (DIM / 4) + lane];
        acc.x += b * m.x; acc.y += b * m.y; acc.z += b * m.z; acc.w += b * m.w;
    }
    reinterpret_cast<float4*>(out + (size_t)tok * DIM)[lane] = acc;
}

extern "C" void kernel_launch(void* const* d_in, const int* in_sizes, int n_in,
                              void* d_out, int out_size, void* d_ws, size_t ws_size,
                              hipStream_t stream) {
    const int*   token_ids   = (const int*)d_in[0];    // [4, 2048]
    const float* base_emb    = (const float*)d_in[1];  // [32000, 256]
    const float* rule_mats   = (const float*)d_in[2];  // [100, 256, 256]
    const int*   token_rules = (const int*)d_in[3];    // [32000]
    float*       out         = (float*)d_out;          // [4, 2048, 256]

    if (ws_size < WS_BYTES) {
        rule_embed_fallback<<<(NTOK + 3) / 4, 256, 0, stream>>>(
            token_ids, base_emb, rule_mats, token_rules, out, NTOK);
        return;
    }

    int*            ws = (int*)d_ws;
    unsigned short* bf = (unsigned short*)d_ws;

    zero_kernel<<<1, 128, 0, stream>>>(ws);
    conv_scatter_kernel<<<NBLK_A, 256, 0, stream>>>(token_ids, token_rules, rule_mats, ws, bf);
    gemm_kernel<<<8 * GSTR, 256, 0, stream>>>(token_ids, base_emb, ws, bf, out);
}

// Round 11
// 21.993 us; speedup vs baseline: 6.6560x; 1.5507x over previous
//
#include <hip/hip_runtime.h>

// RuleBasedEmbedding round 11: 2-node pipeline.
//   conv_scatter: 800 convert blocks (M f32->bf16, B-fragment order) + 32
//                 scatter blocks. Scatter needs NO pre-zeroed globals: block b
//                 compacts its 256 tokens into private per-rule segments
//                 seg[r][b][*] using LDS cursors, then STORES seg_cnt[r][b].
//                 Fully deterministic (segment order = token order).
//   gemm        : 512-thr blocks (8 waves, 2 col-tiles each -> 2.8 waves/SIMD,
//                 2x round-10 parallelism). Per class (bid&7): sum 32 segment
//                 counts per rule -> chunk prefix; sst via binary search.
//
// out[t][e] = sum_d base[token_ids[t]][d] * M[rule[token_ids[t]]][d][e]
// 8192 tokens, D=256, 100 rules.

#define NTOK   8192
#define NRULE  100
#define DIM    256
#define TCH    32                        // tokens per chunk
#define NSEG   32                        // scatter blocks / segments per rule
#define SEGCAP 256                       // tokens per scatter block
#define GSTR   64                        // gemm blocks per XCD class
#define NCONV  (NRULE * 8)               // 800 convert blocks
#define NBLK_A (NCONV + NSEG)            // 832

// Bfrag: [r][ks=8][ct=16][lane=64][e=8] bf16 = 13,107,200 B
#define BFRAG_U16   (NRULE * 8 * 16 * 64 * 8)
#define WS_SEGCNT   (BFRAG_U16 / 2)              // [r][b] counts: 3200 ints
#define WS_SEGLIST  (WS_SEGCNT + NRULE * NSEG)   // [r][b][slot]: 819200 ints
#define WS_TOTAL_INT (WS_SEGLIST + NRULE * NSEG * SEGCAP)
#define WS_BYTES    ((size_t)WS_TOTAL_INT * 4)   // ~16.4 MB

typedef __attribute__((ext_vector_type(8))) short bf16x8;   // 8 bf16 = 4 VGPR
typedef __attribute__((ext_vector_type(4))) float f32x4;    // MFMA C/D

__device__ __forceinline__ unsigned short f2bf(float f) {
    union { float f; unsigned int u; } c; c.f = f;
    unsigned int u = c.u;
    u = (u + 0x7FFFu + ((u >> 16) & 1u)) >> 16;   // RNE
    return (unsigned short)u;
}

// ---------------- convert + segment-scatter (no global init needed) ----------------
__global__ __launch_bounds__(256)
void conv_scatter_kernel(const int* __restrict__ token_ids,
                         const int* __restrict__ token_rules,
                         const float* __restrict__ M,
                         int* __restrict__ ws,
                         unsigned short* __restrict__ bf) {
    const int tid = threadIdx.x;
    const int bid = blockIdx.x;

    if (bid >= NCONV) {
        // ---- scatter block b: private segments, LDS cursors, plain stores ----
        __shared__ int cur[NRULE];
        const int b = bid - NCONV;
        if (tid < NRULE) cur[tid] = 0;
        __syncthreads();
        const int tok = b * SEGCAP + tid;             // 256 tokens per block
        const int id  = token_ids[tok];
        const int r   = token_rules[id];
        const int slot = atomicAdd(&cur[r], 1);       // LDS atomic, in-block
        ws[WS_SEGLIST + (r * NSEG + b) * SEGCAP + slot] = tok;
        __syncthreads();
        if (tid < NRULE) ws[WS_SEGCNT + tid * NSEG + b] = cur[tid];
        return;
    }

    // ---- convert slab M[r][ks*32..+31][:] -> Bfrag ----
    __shared__ unsigned short sb[32][DIM];        // 16 KB row-major bf16 slab
    const int r  = bid >> 3;
    const int ks = bid & 7;
    const float4* M4 = reinterpret_cast<const float4*>(M) + ((size_t)r * 256 + ks * 32) * 64;
    #pragma unroll
    for (int j = 0; j < 8; ++j) {
        int idx = j * 256 + tid;                  // 32 rows x 64 float4
        int kl = idx >> 6, c4 = idx & 63;
        float4 v = M4[kl * 64 + c4];
        sb[kl][c4 * 4 + 0] = f2bf(v.x);
        sb[kl][c4 * 4 + 1] = f2bf(v.y);
        sb[kl][c4 * 4 + 2] = f2bf(v.z);
        sb[kl][c4 * 4 + 3] = f2bf(v.w);
    }
    __syncthreads();

    // Bfrag[r][ks][ct][l][e] = M[r][ks*32 + (l>>4)*8 + e][ct*16 + (l&15)]
    uint4* outp = reinterpret_cast<uint4*>(bf) + ((size_t)(r * 8 + ks) * 16) * 64;
    #pragma unroll
    for (int it = 0; it < 4; ++it) {
        int w = it * 256 + tid;                   // 16 ct x 64 lanes
        int ct = w >> 6, l = w & 63;
        int kb = (l >> 4) * 8, cc = ct * 16 + (l & 15);
        unsigned int d0 = sb[kb + 0][cc] | ((unsigned int)sb[kb + 1][cc] << 16);
        unsigned int d1 = sb[kb + 2][cc] | ((unsigned int)sb[kb + 3][cc] << 16);
        unsigned int d2 = sb[kb + 4][cc] | ((unsigned int)sb[kb + 5][cc] << 16);
        unsigned int d3 = sb[kb + 6][cc] | ((unsigned int)sb[kb + 7][cc] << 16);
        outp[ct * 64 + l] = make_uint4(d0, d1, d2, d3);
    }
}

// ---------------- gemm: 8 waves/chunk, 2 col-tiles/wave ----------------
__global__ __launch_bounds__(512)
void gemm_kernel(const int* __restrict__ token_ids,
                 const float* __restrict__ base_emb,
                 const int* __restrict__ ws,
                 const unsigned short* __restrict__ bfrag,
                 float* __restrict__ out) {
    const int xcd  = blockIdx.x & 7;
    const int base = blockIdx.x >> 3;               // 0..GSTR-1
    const int tid  = threadIdx.x;
    const int wave = tid >> 6, lane = tid & 63;     // 8 waves

    __shared__ unsigned short sa[8 * 2 * 64 * 8];   // 16 KB: [ks][tt][lane][e]
    __shared__ int sst[TCH];
    __shared__ int s_scnt[13][NSEG];                // per-rule segment counts
    __shared__ int s_soff[13][NSEG + 1];            // per-rule segment prefix
    __shared__ int s_tot[13];
    __shared__ int s_choff[14];

    // build class tables: rules r = xcd + 8*i, i = 0..12
    if (tid < 13 * NSEG) {
        int i = tid >> 5, b = tid & (NSEG - 1);
        int r = xcd + 8 * i;
        s_scnt[i][b] = (r < NRULE) ? ws[WS_SEGCNT + r * NSEG + b] : 0;
    }
    __syncthreads();
    if (tid < 13) {
        int acc = 0;
        #pragma unroll
        for (int b = 0; b < NSEG; ++b) { s_soff[tid][b] = acc; acc += s_scnt[tid][b]; }
        s_soff[tid][NSEG] = acc;
        s_tot[tid] = acc;
    }
    __syncthreads();
    if (tid == 0) {
        int acc = 0; s_choff[0] = 0;
        #pragma unroll
        for (int i = 0; i < 13; ++i) { acc += (s_tot[i] + TCH - 1) / TCH; s_choff[i + 1] = acc; }
    }
    __syncthreads();
    const int total_ch = s_choff[13];

    for (int slot = base; slot < total_ch; slot += GSTR) {
        int i = 0;                                  // largest k with choff[k] <= slot
        #pragma unroll
        for (int k = 1; k < 13; ++k) if (slot >= s_choff[k]) i = k;
        const int r = xcd + 8 * i;
        const int j = slot - s_choff[i];

        __syncthreads();                            // sa/sst safe to overwrite
        if (tid < TCH) {
            int idx = j * TCH + tid;
            int tok = -1;
            if (idx < s_tot[i]) {
                int lo = 0, hi = NSEG - 1;          // largest s with soff[s] <= idx
                while (lo < hi) {
                    int mid = (lo + hi + 1) >> 1;
                    if (s_soff[i][mid] <= idx) lo = mid; else hi = mid - 1;
                }
                tok = ws[WS_SEGLIST + (r * NSEG + lo) * SEGCAP + (idx - s_soff[i][lo])];
            }
            sst[tid] = tok;
        }
        __syncthreads();

        {   // stage A: 512 thr = (token s 0..31) x (k-sixteenth q 0..15)
            const int s = tid >> 4, q = tid & 15;
            const int pos = sst[s];
            const int tt = s >> 4, lr = s & 15;
            const float4* row4 = nullptr;
            if (pos >= 0)
                row4 = reinterpret_cast<const float4*>(base_emb + (size_t)token_ids[pos] * DIM);
            #pragma unroll
            for (int jj = 0; jj < 4; ++jj) {
                float4 v = row4 ? row4[q * 4 + jj] : make_float4(0.f, 0.f, 0.f, 0.f);
                const int k0 = q * 16 + jj * 4;
                const int ks = k0 >> 5, koff = k0 & 31;
                const int l = lr | ((koff >> 3) << 4);
                const int e0 = koff & 7;             // 0 or 4
                ushort4 p;
                p.x = f2bf(v.x); p.y = f2bf(v.y); p.z = f2bf(v.z); p.w = f2bf(v.w);
                *reinterpret_cast<ushort4*>(&sa[((ks * 2 + tt) * 64 + l) * 8 + e0]) = p;
            }
        }
        __syncthreads();

        f32x4 acc[2][2];
        #pragma unroll
        for (int tt = 0; tt < 2; ++tt)
            #pragma unroll
            for (int ctl = 0; ctl < 2; ++ctl)
                acc[tt][ctl] = (f32x4){0.f, 0.f, 0.f, 0.f};

        const bf16x8* Af = reinterpret_cast<const bf16x8*>(sa);
        const bf16x8* Bf = reinterpret_cast<const bf16x8*>(bfrag) + (size_t)r * 8 * 16 * 64;
        const int ct0 = wave * 2;                   // this wave's 2 col-tiles

        #pragma unroll
        for (int ks = 0; ks < 8; ++ks) {
            const bf16x8 a0 = Af[(ks * 2 + 0) * 64 + lane];
            const bf16x8 a1 = Af[(ks * 2 + 1) * 64 + lane];
            const bf16x8 b0 = Bf[(ks * 16 + ct0 + 0) * 64 + lane];
            const bf16x8 b1 = Bf[(ks * 16 + ct0 + 1) * 64 + lane];
            acc[0][0] = __builtin_amdgcn_mfma_f32_16x16x32_bf16(a0, b0, acc[0][0], 0, 0, 0);
            acc[0][1] = __builtin_amdgcn_mfma_f32_16x16x32_bf16(a0, b1, acc[0][1], 0, 0, 0);
            acc[1][0] = __builtin_amdgcn_mfma_f32_16x16x32_bf16(a1, b0, acc[1][0], 0, 0, 0);
            acc[1][1] = __builtin_amdgcn_mfma_f32_16x16x32_bf16(a1, b1, acc[1][1], 0, 0, 0);
        }

        // D layout: col = lane&15, row = (lane>>4)*4 + reg
        #pragma unroll
        for (int tt = 0; tt < 2; ++tt) {
            #pragma unroll
            for (int reg = 0; reg < 4; ++reg) {
                const int row = tt * 16 + (lane >> 4) * 4 + reg;
                const int pos = sst[row];
                if (pos >= 0) {
                    #pragma unroll
                    for (int ctl = 0; ctl < 2; ++ctl) {
                        const int col = (ct0 + ctl) * 16 + (lane & 15);
                        out[(size_t)pos * DIM + col] = acc[tt][ctl][reg];
                    }
                }
            }
        }
    }
}

// ---------------- fallback (round-1 kernel) if ws too small ----------------
__global__ __launch_bounds__(256, 4)
void rule_embed_fallback(const int* __restrict__ token_ids,
                         const float* __restrict__ base_emb,
                         const float* __restrict__ rule_mats,
                         const int* __restrict__ token_rules,
                         float* __restrict__ out, int n_tokens) {
    const int wave = threadIdx.x >> 6, lane = threadIdx.x & 63;
    const int tok = blockIdx.x * 4 + wave;
    __shared__ float base[4][DIM];
    if (tok < n_tokens) {
        const int tid = token_ids[tok];
        reinterpret_cast<float4*>(base[wave])[lane] =
            reinterpret_cast<const float4*>(base_emb + (size_t)tid * DIM)[lane];
    }
    __syncthreads();
    if (tok >= n_tokens) return;
    const int tid = token_ids[tok];
    const int r = token_rules[tid];
    const float4* M4 = reinterpret_cast<const float4*>(rule_mats + (size_t)r * DIM * DIM);
    float4 acc = make_float4(0.f, 0.f, 0.f, 0.f);
    #pragma unroll 8
    for (int d = 0; d < DIM; ++d) {
        const float b = base[wave][d];
        const float4 m = M4[d * (DIM / 4) + lane];
        acc.x += b * m.x; acc.y += b * m.y; acc.z += b * m.z; acc.w += b * m.w;
    }
    reinterpret_cast<float4*>(out + (size_t)tok * DIM)[lane] = acc;
}

extern "C" void kernel_launch(void* const* d_in, const int* in_sizes, int n_in,
                              void* d_out, int out_size, void* d_ws, size_t ws_size,
                              hipStream_t stream) {
    const int*   token_ids   = (const int*)d_in[0];    // [4, 2048]
    const float* base_emb    = (const float*)d_in[1];  // [32000, 256]
    const float* rule_mats   = (const float*)d_in[2];  // [100, 256, 256]
    const int*   token_rules = (const int*)d_in[3];    // [32000]
    float*       out         = (float*)d_out;          // [4, 2048, 256]

    if (ws_size < WS_BYTES) {
        rule_embed_fallback<<<(NTOK + 3) / 4, 256, 0, stream>>>(
            token_ids, base_emb, rule_mats, token_rules, out, NTOK);
        return;
    }

    int*            ws = (int*)d_ws;
    unsigned short* bf = (unsigned short*)d_ws;

    conv_scatter_kernel<<<NBLK_A, 256, 0, stream>>>(token_ids, token_rules, rule_mats, ws, bf);
    gemm_kernel<<<8 * GSTR, 512, 0, stream>>>(token_ids, base_emb, ws, bf, out);
}